// Round 8
// baseline (103.573 us; speedup 1.0000x reference)
//
#include <hip/hip_runtime.h>

#define Hh 512
#define Ww 512
#define NPIX (Hh*Ww)
#define BATCH 4

// ws layout (no initialization required anywhere):
//   bmin: float[4][512]        @ 0      (8 KB)  per-block S min (plain stores)
//   bmax: float[4][512]        @ 8192   (8 KB)  per-block S max
//   hp:   uint [4][64bin][64s] @ 16384  (64 KB) per-block partial histograms (transposed)

__global__ __launch_bounds__(256) void k_hist(const float* __restrict__ in,
                                              unsigned* __restrict__ hp) {
    __shared__ unsigned lh[64];
    const int tid = threadIdx.x;
    if (tid < 64) lh[tid] = 0u;
    __syncthreads();
    const int img = blockIdx.x >> 6, sub = blockIdx.x & 63;
    const float4* Lp = (const float4*)(in + (size_t)img * 3 * NPIX) + sub * 1024;
    #pragma unroll
    for (int t = 0; t < 4; ++t) {
        float4 v = Lp[t*256 + tid];
        float f[4] = {v.x, v.y, v.z, v.w};
        #pragma unroll
        for (int j = 0; j < 4; ++j) {
            float ln = fminf(fmaxf(f[j] / 100.0f, 0.0f), 1.0f);
            int idx = min((int)(ln * 64.0f), 63);
            atomicAdd(&lh[idx], 1u);
        }
    }
    __syncthreads();
    if (tid < 64) hp[((size_t)img*64 + tid)*64 + sub] = lh[tid];   // [img][bin][sub]
}

// Tile 16 wide x 32 tall; block 16x16; 2 output rows/thread.
// Staged: 46 rows x 32 cols at (by-7, bx-8). Packed-bin row stride 9 dwords
// (dword 8 dead; reads of it are fully masked by wm).
__global__ __launch_bounds__(256, 8) void k_main(const float* __restrict__ in,
        const unsigned* __restrict__ hp, float* __restrict__ bmin,
        float* __restrict__ bmax, float* __restrict__ out)
{
    __shared__ unsigned s_pk[46*9];
    __shared__ float s_c[46*36];
    __shared__ float s_cc[32*33];
    __shared__ float s_lnc[32*16];
    __shared__ float lhf[64];
    __shared__ float red[8];

    const int tx = threadIdx.x, ty = threadIdx.y;
    const int tid = ty*16 + tx;
    const int bx = blockIdx.x * 16, by = blockIdx.y * 32;
    const int img = blockIdx.z;
    const float* Lp = in + (size_t)img * 3 * NPIX;

    // ---- phase 0: coalesced hist reduce (all 256 threads, 4 uint4 each) ----
    {
        const int bin = tid >> 2, grp = tid & 3;
        const uint4* p = (const uint4*)(hp + ((size_t)img*64 + bin)*64 + grp*16);
        uint4 x0 = p[0], x1 = p[1], x2 = p[2], x3 = p[3];
        unsigned sum = x0.x+x0.y+x0.z+x0.w + x1.x+x1.y+x1.z+x1.w
                     + x2.x+x2.y+x2.z+x2.w + x3.x+x3.y+x3.z+x3.w;
        sum += __shfl_xor(sum, 1);
        sum += __shfl_xor(sum, 2);
        if (grp == 0) lhf[bin] = (float)sum * (1.0f/262144.0f);
    }

    // ---- per-thread window byte masks (5 dwords, high bit per window byte) ----
    const int s = tx + 1;
    const int j0 = s >> 2;
    const unsigned m20 = 0x7FFFu << (s & 3);
    unsigned wm[5];
    #pragma unroll
    for (int i = 0; i < 5; ++i) {
        unsigned n = (m20 >> (4*i)) & 0xFu;
        wm[i] = (n&1u)*0x80u | (n&2u)*0x4000u | (n&4u)*0x200000u | (n&8u)*0x10000000u;
    }

    // ---- stage 46x32: prefetch ALL global loads into registers first ----
    float4 Lv[2], Av[2], Bv[2];
    bool vld[2];
    #pragma unroll
    for (int it = 0; it < 2; ++it) {
        const int l = tid + it*256;
        const int r = l >> 3, c4 = l & 7;
        const int gy = by - 7 + r, gx0 = bx - 8 + c4*4;
        vld[it] = (l < 368) && gy >= 0 && gy < Hh && gx0 >= 0 && gx0 < Ww;
        if (vld[it]) {
            const int g = gy*Ww + gx0;
            Lv[it] = *(const float4*)(Lp + g);
            Av[it] = *(const float4*)(Lp + NPIX + g);
            Bv[it] = *(const float4*)(Lp + 2*NPIX + g);
        }
    }
    #pragma unroll
    for (int it = 0; it < 2; ++it) {
        const int l = tid + it*256;
        if (l < 368) {
            const int r = l >> 3, c4 = l & 7;
            unsigned pk = 0x7F7F7F7Fu;
            float4 cv = {0.f, 0.f, 0.f, 0.f};
            if (vld[it]) {
                const float l0 = fminf(fmaxf(Lv[it].x / 100.0f, 0.0f), 1.0f);
                const float l1 = fminf(fmaxf(Lv[it].y / 100.0f, 0.0f), 1.0f);
                const float l2 = fminf(fmaxf(Lv[it].z / 100.0f, 0.0f), 1.0f);
                const float l3 = fminf(fmaxf(Lv[it].w / 100.0f, 0.0f), 1.0f);
                const int b0 = min((int)(l0*64.0f), 63), b1 = min((int)(l1*64.0f), 63);
                const int b2 = min((int)(l2*64.0f), 63), b3 = min((int)(l3*64.0f), 63);
                pk = (unsigned)b0 | ((unsigned)b1<<8) | ((unsigned)b2<<16) | ((unsigned)b3<<24);
                const float k255 = 1.0f/255.0f;
                cv.x = (Av[it].x+128.0f)*k255 + (Bv[it].x+128.0f)*k255;
                cv.y = (Av[it].y+128.0f)*k255 + (Bv[it].y+128.0f)*k255;
                cv.z = (Av[it].z+128.0f)*k255 + (Bv[it].z+128.0f)*k255;
                cv.w = (Av[it].w+128.0f)*k255 + (Bv[it].w+128.0f)*k255;
                if (r >= 7 && r < 39 && c4 >= 2 && c4 <= 5) {
                    float4 lv4 = {l0, l1, l2, l3};
                    *(float4*)&s_lnc[(r-7)*16 + 4*(c4-2)] = lv4;
                }
            }
            s_pk[r*9 + c4] = pk;
            *(float4*)&s_c[r*36 + c4*4] = cv;
        }
    }
    __syncthreads();

    // ---- vertical chroma 15-sums, paired output rows ----
    for (int l = tid; l < 512; l += 256) {
        const int q = l >> 5, c = l & 31;
        float mid = 0.f;
        #pragma unroll
        for (int k = 1; k < 15; ++k) mid += s_c[(2*q+k)*36 + c];
        s_cc[(2*q)*33 + c]   = mid + s_c[(2*q)*36 + c];
        s_cc[(2*q+1)*33 + c] = mid + s_c[(2*q+15)*36 + c];
    }
    __syncthreads();

    // ---- own-bin match count: fully unrolled, 4 independent chains ----
    const int r0 = 2*ty;
    const int cbyte = tx + 8;
    const unsigned cb0 = (s_pk[(r0+7)*9 + (cbyte>>2)] >> (8*(cbyte&3))) & 0xFFu;
    const unsigned cb1 = (s_pk[(r0+8)*9 + (cbyte>>2)] >> (8*(cbyte&3))) & 0xFFu;
    const unsigned cb40 = cb0 * 0x01010101u;
    const unsigned cb41 = cb1 * 0x01010101u;
    const unsigned K = 0x7F7F7F7Fu;
    int a0 = 0, a1 = 0, a2 = 0, a3 = 0;
    const unsigned* rp = s_pk + r0*9 + j0;

    #pragma unroll
    for (int k = 0; k < 16; ++k) {
        const unsigned d0 = rp[k*9+0], d1 = rp[k*9+1], d2 = rp[k*9+2],
                       d3 = rp[k*9+3], d4 = rp[k*9+4];
        if (k != 15) {
            a0 += __popc(~((d0^cb40)+K) & wm[0]);
            a1 += __popc(~((d1^cb40)+K) & wm[1]);
            a0 += __popc(~((d2^cb40)+K) & wm[2]);
            a1 += __popc(~((d3^cb40)+K) & wm[3]);
            a0 += __popc(~((d4^cb40)+K) & wm[4]);
        }
        if (k != 0) {
            a2 += __popc(~((d0^cb41)+K) & wm[0]);
            a3 += __popc(~((d1^cb41)+K) & wm[1]);
            a2 += __popc(~((d2^cb41)+K) & wm[2]);
            a3 += __popc(~((d3^cb41)+K) & wm[3]);
            a2 += __popc(~((d4^cb41)+K) & wm[4]);
        }
    }
    const int c0 = a0 + a1, c1 = a2 + a3;

    // ---- horizontal chroma sums ----
    float sc0 = 0.f, sc1 = 0.f;
    const float* ccp = s_cc + r0*33 + s;
    #pragma unroll
    for (int dx = 0; dx < 15; ++dx) { sc0 += ccp[dx]; sc1 += ccp[33+dx]; }

    // ---- epilogue: S (to out second half), L_perp ----
    const int gx = bx + tx;
    const int gy0 = by + r0;
    const int cols  = min(gx+7, Ww-1) - max(gx-7, 0) + 1;
    const int rows0 = min(gy0+7, Hh-1) - max(gy0-7, 0) + 1;
    const int rows1 = min(gy0+8, Hh-1) - max(gy0-6, 0) + 1;
    const float inv0 = __builtin_amdgcn_rcpf((float)(rows0*cols));
    const float inv1 = __builtin_amdgcn_rcpf((float)(rows1*cols));
    const float pg0 = lhf[cb0];
    const float pg1 = lhf[cb1];
    const float S0 = -__logf(0.9f*((float)c0*inv0) + 0.1f*pg0 + 1e-6f);
    const float S1 = -__logf(0.9f*((float)c1*inv1) + 0.1f*pg1 + 1e-6f);
    const int gbase = img*NPIX + gy0*Ww + gx;

    const float lp0 = s_lnc[r0*16 + tx]     - 0.5f*(s_c[(r0+7)*36 + tx+8] - sc0*inv0);
    const float lp1 = s_lnc[(r0+1)*16 + tx] - 0.5f*(s_c[(r0+8)*36 + tx+8] - sc1*inv1);
    out[gbase]      = fminf(fmaxf(lp0, 0.f), 1.f);
    out[gbase + Ww] = fminf(fmaxf(lp1, 0.f), 1.f);
    float* outN = out + (size_t)BATCH*NPIX;
    outN[gbase]      = S0;     // unnormalized S; k_norm normalizes in place
    outN[gbase + Ww] = S1;

    // ---- block min/max of S -> plain per-block stores (no atomics/init) ----
    float smin = fminf(S0, S1), smax = fmaxf(S0, S1);
    #pragma unroll
    for (int off = 32; off >= 1; off >>= 1) {
        smin = fminf(smin, __shfl_xor(smin, off));
        smax = fmaxf(smax, __shfl_xor(smax, off));
    }
    const int wid = tid >> 6;
    if ((tid & 63) == 0) { red[wid] = smin; red[4+wid] = smax; }
    __syncthreads();
    if (tid == 0) {
        const int bid = blockIdx.y*32 + blockIdx.x;   // 512 blocks/image
        bmin[img*512 + bid] = fminf(fminf(red[0],red[1]), fminf(red[2],red[3]));
        bmax[img*512 + bid] = fmaxf(fmaxf(red[4],red[5]), fmaxf(red[6],red[7]));
    }
}

// In-place normalize of outN. 1024 blocks x 256 threads; 1 float4/thread.
__global__ __launch_bounds__(256) void k_norm(float* __restrict__ outN,
        const float* __restrict__ bmin, const float* __restrict__ bmax) {
    __shared__ float red[8];
    const int tid = threadIdx.x;
    const int img = blockIdx.x >> 8;

    float mn = __builtin_inff(), mx = -__builtin_inff();
    if (tid < 128) {
        float4 a = ((const float4*)(bmin + img*512))[tid];
        float4 b = ((const float4*)(bmax + img*512))[tid];
        mn = fminf(fminf(a.x, a.y), fminf(a.z, a.w));
        mx = fmaxf(fmaxf(b.x, b.y), fmaxf(b.z, b.w));
    }
    #pragma unroll
    for (int off = 32; off >= 1; off >>= 1) {
        mn = fminf(mn, __shfl_xor(mn, off));
        mx = fmaxf(mx, __shfl_xor(mx, off));
    }
    if ((tid & 63) == 0) { red[tid>>6] = mn; red[4 + (tid>>6)] = mx; }
    __syncthreads();
    const float vmin = fminf(fminf(red[0],red[1]), fminf(red[2],red[3]));
    const float vmax = fmaxf(fmaxf(red[4],red[5]), fmaxf(red[6],red[7]));
    const float inv = 1.0f / (vmax - vmin + 1e-6f);

    float4* p = (float4*)outN + (size_t)blockIdx.x*256;
    float4 v = p[tid];
    v.x = (v.x - vmin) * inv; v.y = (v.y - vmin) * inv;
    v.z = (v.z - vmin) * inv; v.w = (v.w - vmin) * inv;
    p[tid] = v;
}

extern "C" void kernel_launch(void* const* d_in, const int* in_sizes, int n_in,
                              void* d_out, int out_size, void* d_ws, size_t ws_size,
                              hipStream_t stream) {
    const float* in = (const float*)d_in[0];
    float* out = (float*)d_out;
    float* bmin = (float*)d_ws;                          // 8 KB
    float* bmax = bmin + BATCH*512;                      // 8 KB
    unsigned* hp = (unsigned*)(bmax + BATCH*512);        // 64 KB

    k_hist<<<BATCH*64, 256, 0, stream>>>(in, hp);
    dim3 grid(Ww/16, Hh/32, BATCH), blk(16, 16);
    // ATTRIBUTION PROBE: k_main launched twice (idempotent — identical outputs).
    // dur_us(this round) - dur_us(R6) = k_main duration + 1 node overhead.
    k_main<<<grid, blk, 0, stream>>>(in, hp, bmin, bmax, out);
    k_main<<<grid, blk, 0, stream>>>(in, hp, bmin, bmax, out);
    k_norm<<<BATCH*256, 256, 0, stream>>>(out + (size_t)BATCH*NPIX, bmin, bmax);
}

// Round 9
// 95.226 us; speedup vs baseline: 1.0876x; 1.0876x over previous
//
#include <hip/hip_runtime.h>

#define Hh 512
#define Ww 512
#define NPIX (Hh*Ww)
#define BATCH 4

// ws layout (no initialization required anywhere):
//   bmin: float[4][512]        @ 0      (8 KB)  per-block S min (plain stores)
//   bmax: float[4][512]        @ 8192   (8 KB)  per-block S max
//   hp:   uint [4][64bin][64s] @ 16384  (64 KB) per-block partial histograms (transposed)

__global__ __launch_bounds__(256) void k_hist(const float* __restrict__ in,
                                              unsigned* __restrict__ hp) {
    __shared__ unsigned lh[64];
    const int tid = threadIdx.x;
    if (tid < 64) lh[tid] = 0u;
    __syncthreads();
    const int img = blockIdx.x >> 6, sub = blockIdx.x & 63;
    const float4* Lp = (const float4*)(in + (size_t)img * 3 * NPIX) + sub * 1024;
    #pragma unroll
    for (int t = 0; t < 4; ++t) {
        float4 v = Lp[t*256 + tid];
        float f[4] = {v.x, v.y, v.z, v.w};
        #pragma unroll
        for (int j = 0; j < 4; ++j) {
            float ln = fminf(fmaxf(f[j] / 100.0f, 0.0f), 1.0f);
            int idx = min((int)(ln * 64.0f), 63);
            atomicAdd(&lh[idx], 1u);
        }
    }
    __syncthreads();
    if (tid < 64) hp[((size_t)img*64 + tid)*64 + sub] = lh[tid];   // [img][bin][sub]
}

// Tile 16 wide x 32 tall; block 16x16; 2 output rows/thread.
// Staged: 46 rows x 32 cols at (by-7, bx-8). Packed-bin row stride 9 dwords
// (dword 8 dead; reads of it are fully masked by wm).
__global__ __launch_bounds__(256, 8) void k_main(const float* __restrict__ in,
        const unsigned* __restrict__ hp, float* __restrict__ bmin,
        float* __restrict__ bmax, float* __restrict__ out)
{
    __shared__ unsigned s_pk[46*9];
    __shared__ float s_c[46*36];
    __shared__ float s_cc[32*33];
    __shared__ float s_lnc[32*16];
    __shared__ float lhf[64];
    __shared__ float red[8];

    const int tx = threadIdx.x, ty = threadIdx.y;
    const int tid = ty*16 + tx;
    const int bx = blockIdx.x * 16, by = blockIdx.y * 32;
    const int img = blockIdx.z;
    const float* Lp = in + (size_t)img * 3 * NPIX;

    // ---- phase 0: coalesced hist reduce (all 256 threads, 4 uint4 each) ----
    {
        const int bin = tid >> 2, grp = tid & 3;
        const uint4* p = (const uint4*)(hp + ((size_t)img*64 + bin)*64 + grp*16);
        uint4 x0 = p[0], x1 = p[1], x2 = p[2], x3 = p[3];
        unsigned sum = x0.x+x0.y+x0.z+x0.w + x1.x+x1.y+x1.z+x1.w
                     + x2.x+x2.y+x2.z+x2.w + x3.x+x3.y+x3.z+x3.w;
        sum += __shfl_xor(sum, 1);
        sum += __shfl_xor(sum, 2);
        if (grp == 0) lhf[bin] = (float)sum * (1.0f/262144.0f);
    }

    // ---- per-thread window byte masks (5 dwords, high bit per window byte) ----
    const int s = tx + 1;
    const int j0 = s >> 2;
    const unsigned m20 = 0x7FFFu << (s & 3);
    unsigned wm[5];
    #pragma unroll
    for (int i = 0; i < 5; ++i) {
        unsigned n = (m20 >> (4*i)) & 0xFu;
        wm[i] = (n&1u)*0x80u | (n&2u)*0x4000u | (n&4u)*0x200000u | (n&8u)*0x10000000u;
    }

    // ---- stage 46x32: prefetch ALL global loads into registers first ----
    float4 Lv[2], Av[2], Bv[2];
    bool vld[2];
    #pragma unroll
    for (int it = 0; it < 2; ++it) {
        const int l = tid + it*256;
        const int r = l >> 3, c4 = l & 7;
        const int gy = by - 7 + r, gx0 = bx - 8 + c4*4;
        vld[it] = (l < 368) && gy >= 0 && gy < Hh && gx0 >= 0 && gx0 < Ww;
        if (vld[it]) {
            const int g = gy*Ww + gx0;
            Lv[it] = *(const float4*)(Lp + g);
            Av[it] = *(const float4*)(Lp + NPIX + g);
            Bv[it] = *(const float4*)(Lp + 2*NPIX + g);
        }
    }
    #pragma unroll
    for (int it = 0; it < 2; ++it) {
        const int l = tid + it*256;
        if (l < 368) {
            const int r = l >> 3, c4 = l & 7;
            unsigned pk = 0x7F7F7F7Fu;
            float4 cv = {0.f, 0.f, 0.f, 0.f};
            if (vld[it]) {
                const float l0 = fminf(fmaxf(Lv[it].x / 100.0f, 0.0f), 1.0f);
                const float l1 = fminf(fmaxf(Lv[it].y / 100.0f, 0.0f), 1.0f);
                const float l2 = fminf(fmaxf(Lv[it].z / 100.0f, 0.0f), 1.0f);
                const float l3 = fminf(fmaxf(Lv[it].w / 100.0f, 0.0f), 1.0f);
                const int b0 = min((int)(l0*64.0f), 63), b1 = min((int)(l1*64.0f), 63);
                const int b2 = min((int)(l2*64.0f), 63), b3 = min((int)(l3*64.0f), 63);
                pk = (unsigned)b0 | ((unsigned)b1<<8) | ((unsigned)b2<<16) | ((unsigned)b3<<24);
                const float k255 = 1.0f/255.0f;
                cv.x = (Av[it].x+128.0f)*k255 + (Bv[it].x+128.0f)*k255;
                cv.y = (Av[it].y+128.0f)*k255 + (Bv[it].y+128.0f)*k255;
                cv.z = (Av[it].z+128.0f)*k255 + (Bv[it].z+128.0f)*k255;
                cv.w = (Av[it].w+128.0f)*k255 + (Bv[it].w+128.0f)*k255;
                if (r >= 7 && r < 39 && c4 >= 2 && c4 <= 5) {
                    float4 lv4 = {l0, l1, l2, l3};
                    *(float4*)&s_lnc[(r-7)*16 + 4*(c4-2)] = lv4;
                }
            }
            s_pk[r*9 + c4] = pk;
            *(float4*)&s_c[r*36 + c4*4] = cv;
        }
    }
    __syncthreads();

    // ---- vertical chroma 15-sums, paired output rows ----
    for (int l = tid; l < 512; l += 256) {
        const int q = l >> 5, c = l & 31;
        float mid = 0.f;
        #pragma unroll
        for (int k = 1; k < 15; ++k) mid += s_c[(2*q+k)*36 + c];
        s_cc[(2*q)*33 + c]   = mid + s_c[(2*q)*36 + c];
        s_cc[(2*q+1)*33 + c] = mid + s_c[(2*q+15)*36 + c];
    }
    __syncthreads();

    // ---- own-bin match count: fully unrolled, 4 independent chains ----
    const int r0 = 2*ty;
    const int cbyte = tx + 8;
    const unsigned cb0 = (s_pk[(r0+7)*9 + (cbyte>>2)] >> (8*(cbyte&3))) & 0xFFu;
    const unsigned cb1 = (s_pk[(r0+8)*9 + (cbyte>>2)] >> (8*(cbyte&3))) & 0xFFu;
    const unsigned cb40 = cb0 * 0x01010101u;
    const unsigned cb41 = cb1 * 0x01010101u;
    const unsigned K = 0x7F7F7F7Fu;
    int a0 = 0, a1 = 0, a2 = 0, a3 = 0;
    const unsigned* rp = s_pk + r0*9 + j0;

    #pragma unroll
    for (int k = 0; k < 16; ++k) {
        const unsigned d0 = rp[k*9+0], d1 = rp[k*9+1], d2 = rp[k*9+2],
                       d3 = rp[k*9+3], d4 = rp[k*9+4];
        if (k != 15) {
            a0 += __popc(~((d0^cb40)+K) & wm[0]);
            a1 += __popc(~((d1^cb40)+K) & wm[1]);
            a0 += __popc(~((d2^cb40)+K) & wm[2]);
            a1 += __popc(~((d3^cb40)+K) & wm[3]);
            a0 += __popc(~((d4^cb40)+K) & wm[4]);
        }
        if (k != 0) {
            a2 += __popc(~((d0^cb41)+K) & wm[0]);
            a3 += __popc(~((d1^cb41)+K) & wm[1]);
            a2 += __popc(~((d2^cb41)+K) & wm[2]);
            a3 += __popc(~((d3^cb41)+K) & wm[3]);
            a2 += __popc(~((d4^cb41)+K) & wm[4]);
        }
    }
    const int c0 = a0 + a1, c1 = a2 + a3;

    // ---- horizontal chroma sums ----
    float sc0 = 0.f, sc1 = 0.f;
    const float* ccp = s_cc + r0*33 + s;
    #pragma unroll
    for (int dx = 0; dx < 15; ++dx) { sc0 += ccp[dx]; sc1 += ccp[33+dx]; }

    // ---- epilogue: S (to out second half), L_perp ----
    const int gx = bx + tx;
    const int gy0 = by + r0;
    const int cols  = min(gx+7, Ww-1) - max(gx-7, 0) + 1;
    const int rows0 = min(gy0+7, Hh-1) - max(gy0-7, 0) + 1;
    const int rows1 = min(gy0+8, Hh-1) - max(gy0-6, 0) + 1;
    const float inv0 = __builtin_amdgcn_rcpf((float)(rows0*cols));
    const float inv1 = __builtin_amdgcn_rcpf((float)(rows1*cols));
    const float pg0 = lhf[cb0];
    const float pg1 = lhf[cb1];
    const float S0 = -__logf(0.9f*((float)c0*inv0) + 0.1f*pg0 + 1e-6f);
    const float S1 = -__logf(0.9f*((float)c1*inv1) + 0.1f*pg1 + 1e-6f);
    const int gbase = img*NPIX + gy0*Ww + gx;

    const float lp0 = s_lnc[r0*16 + tx]     - 0.5f*(s_c[(r0+7)*36 + tx+8] - sc0*inv0);
    const float lp1 = s_lnc[(r0+1)*16 + tx] - 0.5f*(s_c[(r0+8)*36 + tx+8] - sc1*inv1);
    out[gbase]      = fminf(fmaxf(lp0, 0.f), 1.f);
    out[gbase + Ww] = fminf(fmaxf(lp1, 0.f), 1.f);
    float* outN = out + (size_t)BATCH*NPIX;
    outN[gbase]      = S0;     // unnormalized S; k_norm normalizes in place
    outN[gbase + Ww] = S1;

    // ---- block min/max of S -> plain per-block stores (no atomics/init) ----
    float smin = fminf(S0, S1), smax = fmaxf(S0, S1);
    #pragma unroll
    for (int off = 32; off >= 1; off >>= 1) {
        smin = fminf(smin, __shfl_xor(smin, off));
        smax = fmaxf(smax, __shfl_xor(smax, off));
    }
    const int wid = tid >> 6;
    if ((tid & 63) == 0) { red[wid] = smin; red[4+wid] = smax; }
    __syncthreads();
    if (tid == 0) {
        const int bid = blockIdx.y*32 + blockIdx.x;   // 512 blocks/image
        bmin[img*512 + bid] = fminf(fminf(red[0],red[1]), fminf(red[2],red[3]));
        bmax[img*512 + bid] = fmaxf(fmaxf(red[4],red[5]), fmaxf(red[6],red[7]));
    }
}

// In-place normalize of outN. 1024 blocks x 256 threads; 1 float4/thread.
__global__ __launch_bounds__(256) void k_norm(float* __restrict__ outN,
        const float* __restrict__ bmin, const float* __restrict__ bmax) {
    __shared__ float red[8];
    const int tid = threadIdx.x;
    const int img = blockIdx.x >> 8;

    float mn = __builtin_inff(), mx = -__builtin_inff();
    if (tid < 128) {
        float4 a = ((const float4*)(bmin + img*512))[tid];
        float4 b = ((const float4*)(bmax + img*512))[tid];
        mn = fminf(fminf(a.x, a.y), fminf(a.z, a.w));
        mx = fmaxf(fmaxf(b.x, b.y), fmaxf(b.z, b.w));
    }
    #pragma unroll
    for (int off = 32; off >= 1; off >>= 1) {
        mn = fminf(mn, __shfl_xor(mn, off));
        mx = fmaxf(mx, __shfl_xor(mx, off));
    }
    if ((tid & 63) == 0) { red[tid>>6] = mn; red[4 + (tid>>6)] = mx; }
    __syncthreads();
    const float vmin = fminf(fminf(red[0],red[1]), fminf(red[2],red[3]));
    const float vmax = fmaxf(fmaxf(red[4],red[5]), fmaxf(red[6],red[7]));
    const float inv = 1.0f / (vmax - vmin + 1e-6f);

    float4* p = (float4*)outN + (size_t)blockIdx.x*256;
    float4 v = p[tid];
    v.x = (v.x - vmin) * inv; v.y = (v.y - vmin) * inv;
    v.z = (v.z - vmin) * inv; v.w = (v.w - vmin) * inv;
    p[tid] = v;
}

extern "C" void kernel_launch(void* const* d_in, const int* in_sizes, int n_in,
                              void* d_out, int out_size, void* d_ws, size_t ws_size,
                              hipStream_t stream) {
    const float* in = (const float*)d_in[0];
    float* out = (float*)d_out;
    float* bmin = (float*)d_ws;                          // 8 KB
    float* bmax = bmin + BATCH*512;                      // 8 KB
    unsigned* hp = (unsigned*)(bmax + BATCH*512);        // 64 KB

    // ATTRIBUTION PROBE: k_hist launched 5x (idempotent — plain stores of
    // deterministic partials). dur_us(R9) - dur_us(R6) = 4 * (k_hist + node).
    k_hist<<<BATCH*64, 256, 0, stream>>>(in, hp);
    k_hist<<<BATCH*64, 256, 0, stream>>>(in, hp);
    k_hist<<<BATCH*64, 256, 0, stream>>>(in, hp);
    k_hist<<<BATCH*64, 256, 0, stream>>>(in, hp);
    k_hist<<<BATCH*64, 256, 0, stream>>>(in, hp);
    dim3 grid(Ww/16, Hh/32, BATCH), blk(16, 16);
    k_main<<<grid, blk, 0, stream>>>(in, hp, bmin, bmax, out);
    k_norm<<<BATCH*256, 256, 0, stream>>>(out + (size_t)BATCH*NPIX, bmin, bmax);
}

// Round 10
// 84.697 us; speedup vs baseline: 1.2229x; 1.1243x over previous
//
#include <hip/hip_runtime.h>

#define Hh 512
#define Ww 512
#define NPIX (Hh*Ww)
#define BATCH 4

// ws layout (no initialization required anywhere):
//   bmin: float[4][256]        @ 0      (4 KB)  per-block S min (plain stores)
//   bmax: float[4][256]        @ 4096   (4 KB)  per-block S max
//   hp:   uint [4][64bin][64s] @ 8192   (64 KB) per-block partial histograms (transposed)

__global__ __launch_bounds__(256) void k_hist(const float* __restrict__ in,
                                              unsigned* __restrict__ hp) {
    __shared__ unsigned lh[64];
    const int tid = threadIdx.x;
    if (tid < 64) lh[tid] = 0u;
    __syncthreads();
    const int img = blockIdx.x >> 6, sub = blockIdx.x & 63;
    const float4* Lp = (const float4*)(in + (size_t)img * 3 * NPIX) + sub * 1024;
    #pragma unroll
    for (int t = 0; t < 4; ++t) {
        float4 v = Lp[t*256 + tid];
        float f[4] = {v.x, v.y, v.z, v.w};
        #pragma unroll
        for (int j = 0; j < 4; ++j) {
            float ln = fminf(fmaxf(f[j] / 100.0f, 0.0f), 1.0f);
            int idx = min((int)(ln * 64.0f), 63);
            atomicAdd(&lh[idx], 1u);
        }
    }
    __syncthreads();
    if (tid < 64) hp[((size_t)img*64 + tid)*64 + sub] = lh[tid];   // [img][bin][sub]
}

// Tile 32 wide x 32 tall; block 16x16; 4 outputs/thread (2 rows x 2 cols).
// Staged: 46 rows x 48 cols at (by-7, bx-8). Packed-bin row stride 13 dwords
// (dwords 0..11 = bins, dword 12 garbage — tail bytes masked by wm; carries
// from garbage bytes only propagate upward, never into window bytes).
// Column B's window (bytes tx+17..tx+31) is exactly 4 dwords above column A's
// (bytes tx+1..tx+15), so the same 5 masks serve both on dwords d0..d4 / d4..d8.
__global__ __launch_bounds__(256, 4) void k_main(const float* __restrict__ in,
        const unsigned* __restrict__ hp, float* __restrict__ bmin,
        float* __restrict__ bmax, float* __restrict__ out)
{
    __shared__ unsigned s_pk[46*13];
    __shared__ float s_c[46*50];
    __shared__ float s_cc[32*49];
    __shared__ float s_lnc[32*32];
    __shared__ float lhf[64];
    __shared__ float red[8];

    const int tx = threadIdx.x, ty = threadIdx.y;
    const int tid = ty*16 + tx;
    const int bx = blockIdx.x * 32, by = blockIdx.y * 32;
    const int img = blockIdx.z;
    const float* Lp = in + (size_t)img * 3 * NPIX;

    // ---- phase 0: coalesced hist reduce (all 256 threads, 4 uint4 each) ----
    {
        const int bin = tid >> 2, grp = tid & 3;
        const uint4* p = (const uint4*)(hp + ((size_t)img*64 + bin)*64 + grp*16);
        uint4 x0 = p[0], x1 = p[1], x2 = p[2], x3 = p[3];
        unsigned sum = x0.x+x0.y+x0.z+x0.w + x1.x+x1.y+x1.z+x1.w
                     + x2.x+x2.y+x2.z+x2.w + x3.x+x3.y+x3.z+x3.w;
        sum += __shfl_xor(sum, 1);
        sum += __shfl_xor(sum, 2);
        if (grp == 0) lhf[bin] = (float)sum * (1.0f/262144.0f);
    }

    // ---- per-thread window byte masks (5 dwords, high bit per window byte) ----
    const int s = tx + 1;
    const int j0 = s >> 2;
    const unsigned m20 = 0x7FFFu << (s & 3);
    unsigned wm[5];
    #pragma unroll
    for (int i = 0; i < 5; ++i) {
        unsigned n = (m20 >> (4*i)) & 0xFu;
        wm[i] = (n&1u)*0x80u | (n&2u)*0x4000u | (n&4u)*0x200000u | (n&8u)*0x10000000u;
    }

    // ---- stage 46x48 (552 quads): prefetch all global loads first ----
    float4 Lv[3], Av[3], Bv[3];
    bool vld[3];
    #pragma unroll
    for (int it = 0; it < 3; ++it) {
        const int l = tid + it*256;
        const int r = l / 12, c4 = l - r*12;
        const int gy = by - 7 + r, gx0 = bx - 8 + c4*4;
        vld[it] = (l < 552) && gy >= 0 && gy < Hh && gx0 >= 0 && gx0 < Ww;
        if (vld[it]) {
            const int g = gy*Ww + gx0;
            Lv[it] = *(const float4*)(Lp + g);
            Av[it] = *(const float4*)(Lp + NPIX + g);
            Bv[it] = *(const float4*)(Lp + 2*NPIX + g);
        }
    }
    #pragma unroll
    for (int it = 0; it < 3; ++it) {
        const int l = tid + it*256;
        if (l < 552) {
            const int r = l / 12, c4 = l - r*12;
            unsigned pk = 0x7F7F7F7Fu;
            float4 cv = {0.f, 0.f, 0.f, 0.f};
            if (vld[it]) {
                const float l0 = fminf(fmaxf(Lv[it].x / 100.0f, 0.0f), 1.0f);
                const float l1 = fminf(fmaxf(Lv[it].y / 100.0f, 0.0f), 1.0f);
                const float l2 = fminf(fmaxf(Lv[it].z / 100.0f, 0.0f), 1.0f);
                const float l3 = fminf(fmaxf(Lv[it].w / 100.0f, 0.0f), 1.0f);
                const int b0 = min((int)(l0*64.0f), 63), b1 = min((int)(l1*64.0f), 63);
                const int b2 = min((int)(l2*64.0f), 63), b3 = min((int)(l3*64.0f), 63);
                pk = (unsigned)b0 | ((unsigned)b1<<8) | ((unsigned)b2<<16) | ((unsigned)b3<<24);
                const float k255 = 1.0f/255.0f;
                cv.x = (Av[it].x+128.0f)*k255 + (Bv[it].x+128.0f)*k255;
                cv.y = (Av[it].y+128.0f)*k255 + (Bv[it].y+128.0f)*k255;
                cv.z = (Av[it].z+128.0f)*k255 + (Bv[it].z+128.0f)*k255;
                cv.w = (Av[it].w+128.0f)*k255 + (Bv[it].w+128.0f)*k255;
                if (r >= 7 && r < 39 && c4 >= 2 && c4 <= 9) {
                    float4 lv4 = {l0, l1, l2, l3};
                    *(float4*)&s_lnc[(r-7)*32 + 4*(c4-2)] = lv4;
                }
            }
            s_pk[r*13 + c4] = pk;
            *(float4*)&s_c[r*50 + c4*4] = cv;
        }
    }
    __syncthreads();

    // ---- vertical chroma 15-sums, paired output rows: 16 pairs x 48 cols ----
    #pragma unroll
    for (int l0i = 0; l0i < 3; ++l0i) {
        const int l = tid + l0i*256;          // 768 tasks exactly
        const int q = l & 15, c = l >> 4;     // q: row pair, c: 0..47
        float mid = 0.f;
        #pragma unroll
        for (int k = 1; k < 15; ++k) mid += s_c[(2*q+k)*50 + c];
        s_cc[(2*q)*49 + c]   = mid + s_c[(2*q)*50 + c];
        s_cc[(2*q+1)*49 + c] = mid + s_c[(2*q+15)*50 + c];
    }
    __syncthreads();

    // ---- own-bin match: 9 dwords/row serve 4 outputs, 8 indep chains ----
    const int r0 = 2*ty;
    const int dwA = (tx+8) >> 2,  shA = 8*((tx+8)&3);
    const int dwB = (tx+24) >> 2, shB = 8*((tx+24)&3);
    const unsigned binA0 = (s_pk[(r0+7)*13 + dwA] >> shA) & 0xFFu;
    const unsigned binA1 = (s_pk[(r0+8)*13 + dwA] >> shA) & 0xFFu;
    const unsigned binB0 = (s_pk[(r0+7)*13 + dwB] >> shB) & 0xFFu;
    const unsigned binB1 = (s_pk[(r0+8)*13 + dwB] >> shB) & 0xFFu;
    const unsigned cA0 = binA0*0x01010101u, cA1 = binA1*0x01010101u;
    const unsigned cB0 = binB0*0x01010101u, cB1 = binB1*0x01010101u;
    const unsigned K = 0x7F7F7F7Fu;
    int pA0=0, qA0=0, pA1=0, qA1=0, pB0=0, qB0=0, pB1=0, qB1=0;
    const unsigned* rp = s_pk + r0*13 + j0;

    #pragma unroll
    for (int k = 0; k < 16; ++k) {
        const unsigned d0 = rp[k*13+0], d1 = rp[k*13+1], d2 = rp[k*13+2],
                       d3 = rp[k*13+3], d4 = rp[k*13+4], d5 = rp[k*13+5],
                       d6 = rp[k*13+6], d7 = rp[k*13+7], d8 = rp[k*13+8];
        if (k != 15) {
            pA0 += __popc(~((d0^cA0)+K) & wm[0]);
            qA0 += __popc(~((d1^cA0)+K) & wm[1]);
            pA0 += __popc(~((d2^cA0)+K) & wm[2]);
            qA0 += __popc(~((d3^cA0)+K) & wm[3]);
            pA0 += __popc(~((d4^cA0)+K) & wm[4]);
            pB0 += __popc(~((d4^cB0)+K) & wm[0]);
            qB0 += __popc(~((d5^cB0)+K) & wm[1]);
            pB0 += __popc(~((d6^cB0)+K) & wm[2]);
            qB0 += __popc(~((d7^cB0)+K) & wm[3]);
            pB0 += __popc(~((d8^cB0)+K) & wm[4]);
        }
        if (k != 0) {
            pA1 += __popc(~((d0^cA1)+K) & wm[0]);
            qA1 += __popc(~((d1^cA1)+K) & wm[1]);
            pA1 += __popc(~((d2^cA1)+K) & wm[2]);
            qA1 += __popc(~((d3^cA1)+K) & wm[3]);
            pA1 += __popc(~((d4^cA1)+K) & wm[4]);
            pB1 += __popc(~((d4^cB1)+K) & wm[0]);
            qB1 += __popc(~((d5^cB1)+K) & wm[1]);
            pB1 += __popc(~((d6^cB1)+K) & wm[2]);
            qB1 += __popc(~((d7^cB1)+K) & wm[3]);
            pB1 += __popc(~((d8^cB1)+K) & wm[4]);
        }
    }
    const int cntA0 = pA0+qA0, cntA1 = pA1+qA1, cntB0 = pB0+qB0, cntB1 = pB1+qB1;

    // ---- horizontal chroma sums: cols [s,s+14] (A) and [s+16,s+30] (B) ----
    float scA0 = 0.f, scA1 = 0.f, scB0 = 0.f, scB1 = 0.f;
    const float* cc0 = s_cc + r0*49 + s;
    const float* cc1 = cc0 + 49;
    #pragma unroll
    for (int dx = 0; dx < 15; ++dx) {
        scA0 += cc0[dx];    scA1 += cc1[dx];
        scB0 += cc0[16+dx]; scB1 += cc1[16+dx];
    }

    // ---- epilogue: 4 outputs ----
    const int gxA = bx + tx, gxB = gxA + 16;
    const int gy0 = by + r0;
    const int colsA = min(gxA+7, Ww-1) - max(gxA-7, 0) + 1;
    const int colsB = min(gxB+7, Ww-1) - max(gxB-7, 0) + 1;
    const int rows0 = min(gy0+7, Hh-1) - max(gy0-7, 0) + 1;
    const int rows1 = min(gy0+8, Hh-1) - max(gy0-6, 0) + 1;
    const float iA0 = __builtin_amdgcn_rcpf((float)(rows0*colsA));
    const float iA1 = __builtin_amdgcn_rcpf((float)(rows1*colsA));
    const float iB0 = __builtin_amdgcn_rcpf((float)(rows0*colsB));
    const float iB1 = __builtin_amdgcn_rcpf((float)(rows1*colsB));
    const float SA0 = -__logf(0.9f*((float)cntA0*iA0) + 0.1f*lhf[binA0] + 1e-6f);
    const float SA1 = -__logf(0.9f*((float)cntA1*iA1) + 0.1f*lhf[binA1] + 1e-6f);
    const float SB0 = -__logf(0.9f*((float)cntB0*iB0) + 0.1f*lhf[binB0] + 1e-6f);
    const float SB1 = -__logf(0.9f*((float)cntB1*iB1) + 0.1f*lhf[binB1] + 1e-6f);
    const int gbase = img*NPIX + gy0*Ww + gxA;
    float* outN = out + (size_t)BATCH*NPIX;
    outN[gbase]          = SA0;
    outN[gbase + 16]     = SB0;
    outN[gbase + Ww]     = SA1;
    outN[gbase + Ww + 16]= SB1;

    const float lpA0 = s_lnc[r0*32 + tx]       - 0.5f*(s_c[(r0+7)*50 + tx+8]  - scA0*iA0);
    const float lpA1 = s_lnc[(r0+1)*32 + tx]   - 0.5f*(s_c[(r0+8)*50 + tx+8]  - scA1*iA1);
    const float lpB0 = s_lnc[r0*32 + tx+16]    - 0.5f*(s_c[(r0+7)*50 + tx+24] - scB0*iB0);
    const float lpB1 = s_lnc[(r0+1)*32 + tx+16]- 0.5f*(s_c[(r0+8)*50 + tx+24] - scB1*iB1);
    out[gbase]           = fminf(fmaxf(lpA0, 0.f), 1.f);
    out[gbase + 16]      = fminf(fmaxf(lpB0, 0.f), 1.f);
    out[gbase + Ww]      = fminf(fmaxf(lpA1, 0.f), 1.f);
    out[gbase + Ww + 16] = fminf(fmaxf(lpB1, 0.f), 1.f);

    // ---- block min/max of S -> plain per-block stores (no atomics/init) ----
    float smin = fminf(fminf(SA0, SA1), fminf(SB0, SB1));
    float smax = fmaxf(fmaxf(SA0, SA1), fmaxf(SB0, SB1));
    #pragma unroll
    for (int off = 32; off >= 1; off >>= 1) {
        smin = fminf(smin, __shfl_xor(smin, off));
        smax = fmaxf(smax, __shfl_xor(smax, off));
    }
    const int wid = tid >> 6;
    if ((tid & 63) == 0) { red[wid] = smin; red[4+wid] = smax; }
    __syncthreads();
    if (tid == 0) {
        const int bid = blockIdx.y*16 + blockIdx.x;   // 256 blocks/image
        bmin[img*256 + bid] = fminf(fminf(red[0],red[1]), fminf(red[2],red[3]));
        bmax[img*256 + bid] = fmaxf(fmaxf(red[4],red[5]), fmaxf(red[6],red[7]));
    }
}

// In-place normalize of outN. 1024 blocks x 256 threads; 1 float4/thread.
__global__ __launch_bounds__(256) void k_norm(float* __restrict__ outN,
        const float* __restrict__ bmin, const float* __restrict__ bmax) {
    __shared__ float red[2];
    const int tid = threadIdx.x;
    const int img = blockIdx.x >> 8;

    if (tid < 64) {   // wave 0: 64 float4 = 256 partials per image
        float4 a = ((const float4*)(bmin + img*256))[tid];
        float4 b = ((const float4*)(bmax + img*256))[tid];
        float mn = fminf(fminf(a.x, a.y), fminf(a.z, a.w));
        float mx = fmaxf(fmaxf(b.x, b.y), fmaxf(b.z, b.w));
        #pragma unroll
        for (int off = 32; off >= 1; off >>= 1) {
            mn = fminf(mn, __shfl_xor(mn, off));
            mx = fmaxf(mx, __shfl_xor(mx, off));
        }
        if (tid == 0) { red[0] = mn; red[1] = mx; }
    }
    __syncthreads();
    const float vmin = red[0];
    const float inv = 1.0f / (red[1] - vmin + 1e-6f);

    float4* p = (float4*)outN + (size_t)blockIdx.x*256;
    float4 v = p[tid];
    v.x = (v.x - vmin) * inv; v.y = (v.y - vmin) * inv;
    v.z = (v.z - vmin) * inv; v.w = (v.w - vmin) * inv;
    p[tid] = v;
}

extern "C" void kernel_launch(void* const* d_in, const int* in_sizes, int n_in,
                              void* d_out, int out_size, void* d_ws, size_t ws_size,
                              hipStream_t stream) {
    const float* in = (const float*)d_in[0];
    float* out = (float*)d_out;
    float* bmin = (float*)d_ws;                          // 4 KB
    float* bmax = bmin + BATCH*256;                      // 4 KB
    unsigned* hp = (unsigned*)(bmax + BATCH*256);        // 64 KB

    k_hist<<<BATCH*64, 256, 0, stream>>>(in, hp);
    dim3 grid(Ww/32, Hh/32, BATCH), blk(16, 16);
    k_main<<<grid, blk, 0, stream>>>(in, hp, bmin, bmax, out);
    k_norm<<<BATCH*256, 256, 0, stream>>>(out + (size_t)BATCH*NPIX, bmin, bmax);
}

// Round 11
// 84.450 us; speedup vs baseline: 1.2264x; 1.0029x over previous
//
#include <hip/hip_runtime.h>

#define Hh 512
#define Ww 512
#define NPIX (Hh*Ww)
#define BATCH 4

// ws layout (no initialization required anywhere):
//   bmin: float[4][512]        @ 0      (8 KB)  per-block S min (plain stores)
//   bmax: float[4][512]        @ 8192   (8 KB)  per-block S max
//   hp:   uint [4][64bin][64s] @ 16384  (64 KB) per-block partial histograms (transposed)

__global__ __launch_bounds__(256) void k_hist(const float* __restrict__ in,
                                              unsigned* __restrict__ hp) {
    __shared__ unsigned lh[64];
    const int tid = threadIdx.x;
    if (tid < 64) lh[tid] = 0u;
    __syncthreads();
    const int img = blockIdx.x >> 6, sub = blockIdx.x & 63;
    const float4* Lp = (const float4*)(in + (size_t)img * 3 * NPIX) + sub * 1024;
    #pragma unroll
    for (int t = 0; t < 4; ++t) {
        float4 v = Lp[t*256 + tid];
        float f[4] = {v.x, v.y, v.z, v.w};
        #pragma unroll
        for (int j = 0; j < 4; ++j) {
            float ln = fminf(fmaxf(f[j] / 100.0f, 0.0f), 1.0f);
            int idx = min((int)(ln * 64.0f), 63);
            atomicAdd(&lh[idx], 1u);
        }
    }
    __syncthreads();
    if (tid < 64) hp[((size_t)img*64 + tid)*64 + sub] = lh[tid];   // [img][bin][sub]
}

// Tile 16 wide x 32 tall; block 16x16; 2 output rows/thread.
// Staged: 46 rows x 32 cols at (by-7, bx-8). Packed-bin row stride 9 dwords
// (dword 8 dead; reads of it are fully masked by wm).
__global__ __launch_bounds__(256, 8) void k_main(const float* __restrict__ in,
        const unsigned* __restrict__ hp, float* __restrict__ bmin,
        float* __restrict__ bmax, float* __restrict__ out)
{
    __shared__ unsigned s_pk[46*9];
    __shared__ float s_c[46*36];
    __shared__ float s_cc[32*33];
    __shared__ float s_pp[32*33];   // exclusive prefix of s_cc rows
    __shared__ float s_lnc[32*16];
    __shared__ float lhf[64];
    __shared__ float red[8];

    const int tx = threadIdx.x, ty = threadIdx.y;
    const int tid = ty*16 + tx;
    const int bx = blockIdx.x * 16, by = blockIdx.y * 32;
    const int img = blockIdx.z;
    const float* Lp = in + (size_t)img * 3 * NPIX;

    // ---- phase 0: coalesced hist reduce (all 256 threads, 4 uint4 each) ----
    {
        const int bin = tid >> 2, grp = tid & 3;
        const uint4* p = (const uint4*)(hp + ((size_t)img*64 + bin)*64 + grp*16);
        uint4 x0 = p[0], x1 = p[1], x2 = p[2], x3 = p[3];
        unsigned sum = x0.x+x0.y+x0.z+x0.w + x1.x+x1.y+x1.z+x1.w
                     + x2.x+x2.y+x2.z+x2.w + x3.x+x3.y+x3.z+x3.w;
        sum += __shfl_xor(sum, 1);
        sum += __shfl_xor(sum, 2);
        if (grp == 0) lhf[bin] = (float)sum * (1.0f/262144.0f);
    }

    // ---- per-thread window byte masks (5 dwords, high bit per window byte) ----
    const int s = tx + 1;
    const int j0 = s >> 2;
    const unsigned m20 = 0x7FFFu << (s & 3);
    unsigned wm[5];
    #pragma unroll
    for (int i = 0; i < 5; ++i) {
        unsigned n = (m20 >> (4*i)) & 0xFu;
        wm[i] = (n&1u)*0x80u | (n&2u)*0x4000u | (n&4u)*0x200000u | (n&8u)*0x10000000u;
    }

    // ---- stage 46x32: prefetch ALL global loads into registers first ----
    float4 Lv[2], Av[2], Bv[2];
    bool vld[2];
    #pragma unroll
    for (int it = 0; it < 2; ++it) {
        const int l = tid + it*256;
        const int r = l >> 3, c4 = l & 7;
        const int gy = by - 7 + r, gx0 = bx - 8 + c4*4;
        vld[it] = (l < 368) && gy >= 0 && gy < Hh && gx0 >= 0 && gx0 < Ww;
        if (vld[it]) {
            const int g = gy*Ww + gx0;
            Lv[it] = *(const float4*)(Lp + g);
            Av[it] = *(const float4*)(Lp + NPIX + g);
            Bv[it] = *(const float4*)(Lp + 2*NPIX + g);
        }
    }
    #pragma unroll
    for (int it = 0; it < 2; ++it) {
        const int l = tid + it*256;
        if (l < 368) {
            const int r = l >> 3, c4 = l & 7;
            unsigned pk = 0x7F7F7F7Fu;
            float4 cv = {0.f, 0.f, 0.f, 0.f};
            if (vld[it]) {
                const float l0 = fminf(fmaxf(Lv[it].x / 100.0f, 0.0f), 1.0f);
                const float l1 = fminf(fmaxf(Lv[it].y / 100.0f, 0.0f), 1.0f);
                const float l2 = fminf(fmaxf(Lv[it].z / 100.0f, 0.0f), 1.0f);
                const float l3 = fminf(fmaxf(Lv[it].w / 100.0f, 0.0f), 1.0f);
                const int b0 = min((int)(l0*64.0f), 63), b1 = min((int)(l1*64.0f), 63);
                const int b2 = min((int)(l2*64.0f), 63), b3 = min((int)(l3*64.0f), 63);
                pk = (unsigned)b0 | ((unsigned)b1<<8) | ((unsigned)b2<<16) | ((unsigned)b3<<24);
                const float k255 = 1.0f/255.0f;
                cv.x = (Av[it].x+128.0f)*k255 + (Bv[it].x+128.0f)*k255;
                cv.y = (Av[it].y+128.0f)*k255 + (Bv[it].y+128.0f)*k255;
                cv.z = (Av[it].z+128.0f)*k255 + (Bv[it].z+128.0f)*k255;
                cv.w = (Av[it].w+128.0f)*k255 + (Bv[it].w+128.0f)*k255;
                if (r >= 7 && r < 39 && c4 >= 2 && c4 <= 5) {
                    float4 lv4 = {l0, l1, l2, l3};
                    *(float4*)&s_lnc[(r-7)*16 + 4*(c4-2)] = lv4;
                }
            }
            s_pk[r*9 + c4] = pk;
            *(float4*)&s_c[r*36 + c4*4] = cv;
        }
    }
    __syncthreads();

    // ---- vertical chroma 15-sums, paired output rows ----
    for (int l = tid; l < 512; l += 256) {
        const int q = l >> 5, c = l & 31;
        float mid = 0.f;
        #pragma unroll
        for (int k = 1; k < 15; ++k) mid += s_c[(2*q+k)*36 + c];
        s_cc[(2*q)*33 + c]   = mid + s_c[(2*q)*36 + c];
        s_cc[(2*q+1)*33 + c] = mid + s_c[(2*q+15)*36 + c];
    }
    __syncthreads();

    // ---- wave 0: exclusive per-row prefix of s_cc (hidden under match) ----
    if (tid < 32) {
        float run = 0.f;
        const float* cc = s_cc + tid*33;
        float* pp = s_pp + tid*33;
        #pragma unroll
        for (int c = 0; c < 32; ++c) { pp[c] = run; run += cc[c]; }
    }

    // ---- own-bin match: software-pipelined rows, 4 independent chains ----
    const int r0 = 2*ty;
    const int cbyte = tx + 8;
    const unsigned cb0 = (s_pk[(r0+7)*9 + (cbyte>>2)] >> (8*(cbyte&3))) & 0xFFu;
    const unsigned cb1 = (s_pk[(r0+8)*9 + (cbyte>>2)] >> (8*(cbyte&3))) & 0xFFu;
    const unsigned cb40 = cb0 * 0x01010101u;
    const unsigned cb41 = cb1 * 0x01010101u;
    const unsigned K = 0x7F7F7F7Fu;
    int a0 = 0, a1 = 0, a2 = 0, a3 = 0;
    const unsigned* rp = s_pk + r0*9 + j0;

    unsigned c0r = rp[0], c1r = rp[1], c2r = rp[2], c3r = rp[3], c4r = rp[4];
    #pragma unroll
    for (int k = 0; k < 16; ++k) {
        const unsigned d0 = c0r, d1 = c1r, d2 = c2r, d3 = c3r, d4 = c4r;
        if (k != 15) {   // prefetch next row before computing on current
            const unsigned* rn = rp + (k+1)*9;
            c0r = rn[0]; c1r = rn[1]; c2r = rn[2]; c3r = rn[3]; c4r = rn[4];
        }
        if (k != 15) {
            a0 += __popc(~((d0^cb40)+K) & wm[0]);
            a1 += __popc(~((d1^cb40)+K) & wm[1]);
            a0 += __popc(~((d2^cb40)+K) & wm[2]);
            a1 += __popc(~((d3^cb40)+K) & wm[3]);
            a0 += __popc(~((d4^cb40)+K) & wm[4]);
        }
        if (k != 0) {
            a2 += __popc(~((d0^cb41)+K) & wm[0]);
            a3 += __popc(~((d1^cb41)+K) & wm[1]);
            a2 += __popc(~((d2^cb41)+K) & wm[2]);
            a3 += __popc(~((d3^cb41)+K) & wm[3]);
            a2 += __popc(~((d4^cb41)+K) & wm[4]);
        }
    }
    const int c0 = a0 + a1, c1 = a2 + a3;

    __syncthreads();   // s_pp ready (built long ago by wave 0)

    // ---- horizontal chroma sums via prefix difference: 2 reads per row ----
    const float sc0 = s_pp[r0*33 + s+15]     - s_pp[r0*33 + s];
    const float sc1 = s_pp[(r0+1)*33 + s+15] - s_pp[(r0+1)*33 + s];

    // ---- epilogue: S (to out second half), L_perp ----
    const int gx = bx + tx;
    const int gy0 = by + r0;
    const int cols  = min(gx+7, Ww-1) - max(gx-7, 0) + 1;
    const int rows0 = min(gy0+7, Hh-1) - max(gy0-7, 0) + 1;
    const int rows1 = min(gy0+8, Hh-1) - max(gy0-6, 0) + 1;
    const float inv0 = __builtin_amdgcn_rcpf((float)(rows0*cols));
    const float inv1 = __builtin_amdgcn_rcpf((float)(rows1*cols));
    const float pg0 = lhf[cb0];
    const float pg1 = lhf[cb1];
    const float S0 = -__logf(0.9f*((float)c0*inv0) + 0.1f*pg0 + 1e-6f);
    const float S1 = -__logf(0.9f*((float)c1*inv1) + 0.1f*pg1 + 1e-6f);
    const int gbase = img*NPIX + gy0*Ww + gx;

    const float lp0 = s_lnc[r0*16 + tx]     - 0.5f*(s_c[(r0+7)*36 + tx+8] - sc0*inv0);
    const float lp1 = s_lnc[(r0+1)*16 + tx] - 0.5f*(s_c[(r0+8)*36 + tx+8] - sc1*inv1);
    out[gbase]      = fminf(fmaxf(lp0, 0.f), 1.f);
    out[gbase + Ww] = fminf(fmaxf(lp1, 0.f), 1.f);
    float* outN = out + (size_t)BATCH*NPIX;
    outN[gbase]      = S0;     // unnormalized S; k_norm normalizes in place
    outN[gbase + Ww] = S1;

    // ---- block min/max of S -> plain per-block stores (no atomics/init) ----
    float smin = fminf(S0, S1), smax = fmaxf(S0, S1);
    #pragma unroll
    for (int off = 32; off >= 1; off >>= 1) {
        smin = fminf(smin, __shfl_xor(smin, off));
        smax = fmaxf(smax, __shfl_xor(smax, off));
    }
    const int wid = tid >> 6;
    if ((tid & 63) == 0) { red[wid] = smin; red[4+wid] = smax; }
    __syncthreads();
    if (tid == 0) {
        const int bid = blockIdx.y*32 + blockIdx.x;   // 512 blocks/image
        bmin[img*512 + bid] = fminf(fminf(red[0],red[1]), fminf(red[2],red[3]));
        bmax[img*512 + bid] = fmaxf(fmaxf(red[4],red[5]), fmaxf(red[6],red[7]));
    }
}

// In-place normalize of outN. 1024 blocks x 256 threads; 1 float4/thread.
__global__ __launch_bounds__(256) void k_norm(float* __restrict__ outN,
        const float* __restrict__ bmin, const float* __restrict__ bmax) {
    __shared__ float red[8];
    const int tid = threadIdx.x;
    const int img = blockIdx.x >> 8;

    float mn = __builtin_inff(), mx = -__builtin_inff();
    if (tid < 128) {
        float4 a = ((const float4*)(bmin + img*512))[tid];
        float4 b = ((const float4*)(bmax + img*512))[tid];
        mn = fminf(fminf(a.x, a.y), fminf(a.z, a.w));
        mx = fmaxf(fmaxf(b.x, b.y), fmaxf(b.z, b.w));
    }
    #pragma unroll
    for (int off = 32; off >= 1; off >>= 1) {
        mn = fminf(mn, __shfl_xor(mn, off));
        mx = fmaxf(mx, __shfl_xor(mx, off));
    }
    if ((tid & 63) == 0) { red[tid>>6] = mn; red[4 + (tid>>6)] = mx; }
    __syncthreads();
    const float vmin = fminf(fminf(red[0],red[1]), fminf(red[2],red[3]));
    const float vmax = fmaxf(fmaxf(red[4],red[5]), fmaxf(red[6],red[7]));
    const float inv = 1.0f / (vmax - vmin + 1e-6f);

    float4* p = (float4*)outN + (size_t)blockIdx.x*256;
    float4 v = p[tid];
    v.x = (v.x - vmin) * inv; v.y = (v.y - vmin) * inv;
    v.z = (v.z - vmin) * inv; v.w = (v.w - vmin) * inv;
    p[tid] = v;
}

extern "C" void kernel_launch(void* const* d_in, const int* in_sizes, int n_in,
                              void* d_out, int out_size, void* d_ws, size_t ws_size,
                              hipStream_t stream) {
    const float* in = (const float*)d_in[0];
    float* out = (float*)d_out;
    float* bmin = (float*)d_ws;                          // 8 KB
    float* bmax = bmin + BATCH*512;                      // 8 KB
    unsigned* hp = (unsigned*)(bmax + BATCH*512);        // 64 KB

    k_hist<<<BATCH*64, 256, 0, stream>>>(in, hp);
    dim3 grid(Ww/16, Hh/32, BATCH), blk(16, 16);
    k_main<<<grid, blk, 0, stream>>>(in, hp, bmin, bmax, out);
    k_norm<<<BATCH*256, 256, 0, stream>>>(out + (size_t)BATCH*NPIX, bmin, bmax);
}